// Round 1
// baseline (154.300 us; speedup 1.0000x reference)
//
#include <hip/hip_runtime.h>
#include <math.h>

namespace {

constexpr float kA0C0    = 0.8862269254527580f;  // pi / sqrt(4*pi)
constexpr float kA1C1    = 1.7724538509055159f;  // (2*pi/sqrt(3)) * (sqrt(3)/sqrt(4*pi))
constexpr float kA2C2    = 2.4270324670f;        // (2*pi/sqrt(8)) * (3*sqrt(5)/sqrt(12*pi))
constexpr float kAmbient = 0.8f;
constexpr float kSigma   = 1e-4f;
constexpr float kGamma   = 1e-4f;
constexpr float kEps     = 1e-10f;
constexpr float kZnear   = 1.0f;
constexpr float kZfar    = 100.0f;
constexpr int   kK       = 8;

// ---- Pass A: per-vertex SH shading -> shaded vertex colors (V x 3 f32) ----
__global__ void shade_verts_kernel(const float* __restrict__ vn,
                                   const float* __restrict__ vc,
                                   const float* __restrict__ sh,
                                   float* __restrict__ vs, int V) {
  int v = blockIdx.x * blockDim.x + threadIdx.x;
  if (v >= V) return;
  float nx = vn[3 * v + 0], ny = vn[3 * v + 1], nz = vn[3 * v + 2];
  float nrm = fmaxf(sqrtf(nx * nx + ny * ny + nz * nz), 1e-6f);
  nx /= nrm; ny /= nrm; nz /= nrm;
  float Y[9];
  Y[0] = kA0C0;
  Y[1] = -kA1C1 * ny;
  Y[2] =  kA1C1 * nz;
  Y[3] = -kA1C1 * nx;
  Y[4] =  kA2C2 * nx * ny;
  Y[5] = -kA2C2 * ny * nz;
  Y[6] =  kA2C2 * (0.5f / 1.7320508075688772f) * (3.0f * nz * nz - 1.0f);
  Y[7] = -kA2C2 * nx * nz;
  Y[8] =  kA2C2 * 0.5f * (nx * nx - ny * ny);
#pragma unroll
  for (int c = 0; c < 3; ++c) {
    float s = Y[0] * (sh[0 * 3 + c] + kAmbient);
#pragma unroll
    for (int n = 1; n < 9; ++n) s += Y[n] * sh[n * 3 + c];
    vs[3 * v + c] = vc[3 * v + c] * s;
  }
}

// ---- Pass B: gather per-face vertex colors (F x 3verts x 3ch f32) ----
__global__ void face_colors_kernel(const int* __restrict__ faces,
                                   const float* __restrict__ vs,
                                   float* __restrict__ fc, int F) {
  int f = blockIdx.x * blockDim.x + threadIdx.x;
  if (f >= F) return;
  int i0 = faces[3 * f + 0], i1 = faces[3 * f + 1], i2 = faces[3 * f + 2];
#pragma unroll
  for (int c = 0; c < 3; ++c) {
    fc[9 * f + 0 + c] = vs[3 * i0 + c];
    fc[9 * f + 3 + c] = vs[3 * i1 + c];
    fc[9 * f + 6 + c] = vs[3 * i2 + c];
  }
}

// ---- Pass C: per-pixel softmax RGB blend ----
template <bool USE_FC>
__global__ void blend_kernel(const float* __restrict__ bary,
                             const float* __restrict__ zbuf,
                             const float* __restrict__ dists,
                             const int* __restrict__ p2f,
                             const float* __restrict__ fc,     // USE_FC: F x 9
                             const int* __restrict__ faces,    // !USE_FC
                             const float* __restrict__ vs,     // !USE_FC
                             float* __restrict__ out, int P) {
  int p = blockIdx.x * blockDim.x + threadIdx.x;
  if (p >= P) return;

  int4 fA = reinterpret_cast<const int4*>(p2f)[2 * p];
  int4 fB = reinterpret_cast<const int4*>(p2f)[2 * p + 1];
  int f[8] = {fA.x, fA.y, fA.z, fA.w, fB.x, fB.y, fB.z, fB.w};

  float4 zA = reinterpret_cast<const float4*>(zbuf)[2 * p];
  float4 zB = reinterpret_cast<const float4*>(zbuf)[2 * p + 1];
  float z[8] = {zA.x, zA.y, zA.z, zA.w, zB.x, zB.y, zB.z, zB.w};

  float4 dA = reinterpret_cast<const float4*>(dists)[2 * p];
  float4 dB = reinterpret_cast<const float4*>(dists)[2 * p + 1];
  float d[8] = {dA.x, dA.y, dA.z, dA.w, dB.x, dB.y, dB.z, dB.w};

  float4 b4[6];
#pragma unroll
  for (int i = 0; i < 6; ++i)
    b4[i] = reinterpret_cast<const float4*>(bary)[6 * p + i];
  const float* bw = reinterpret_cast<const float*>(b4);

  float prob[8], zi[8];
  float maxz = kEps;
  float alpha = 1.0f;
#pragma unroll
  for (int k = 0; k < 8; ++k) {
    bool m = f[k] >= 0;
    float pr = m ? (1.0f / (1.0f + expf(d[k] / kSigma))) : 0.0f;
    prob[k] = pr;
    alpha *= (1.0f - pr);
    float zv = m ? ((kZfar - z[k]) / (kZfar - kZnear)) : 0.0f;
    zi[k] = zv;
    maxz = fmaxf(maxz, zv);
  }

  float delta = expf((kEps - maxz) / kGamma);
  float denom = delta;
  float cr = 0.0f, cg = 0.0f, cb = 0.0f;
#pragma unroll
  for (int k = 0; k < 8; ++k) {
    float w = prob[k] * expf((zi[k] - maxz) / kGamma);
    denom += w;
    if (f[k] >= 0 && w != 0.0f) {
      float b0 = bw[3 * k + 0], b1 = bw[3 * k + 1], b2 = bw[3 * k + 2];
      float r, g, b;
      if (USE_FC) {
        const float* fp = fc + 9 * f[k];
        r = b0 * fp[0] + b1 * fp[3] + b2 * fp[6];
        g = b0 * fp[1] + b1 * fp[4] + b2 * fp[7];
        b = b0 * fp[2] + b1 * fp[5] + b2 * fp[8];
      } else {
        int i0 = faces[3 * f[k] + 0], i1 = faces[3 * f[k] + 1], i2 = faces[3 * f[k] + 2];
        r = b0 * vs[3 * i0 + 0] + b1 * vs[3 * i1 + 0] + b2 * vs[3 * i2 + 0];
        g = b0 * vs[3 * i0 + 1] + b1 * vs[3 * i1 + 1] + b2 * vs[3 * i2 + 1];
        b = b0 * vs[3 * i0 + 2] + b1 * vs[3 * i1 + 2] + b2 * vs[3 * i2 + 2];
      }
      cr += w * r; cg += w * g; cb += w * b;
    }
  }

  float4 o;
  o.x = (cr + delta) / denom;   // BG = (1,1,1)
  o.y = (cg + delta) / denom;
  o.z = (cb + delta) / denom;
  o.w = 1.0f - alpha;
  reinterpret_cast<float4*>(out)[p] = o;
}

}  // namespace

extern "C" void kernel_launch(void* const* d_in, const int* in_sizes, int n_in,
                              void* d_out, int out_size, void* d_ws, size_t ws_size,
                              hipStream_t stream) {
  const float* vn    = (const float*)d_in[0];
  const float* vc    = (const float*)d_in[1];
  const float* sh    = (const float*)d_in[2];
  const float* bary  = (const float*)d_in[3];
  const float* zbuf  = (const float*)d_in[4];
  const float* dists = (const float*)d_in[5];
  const int*   faces = (const int*)d_in[6];
  const int*   p2f   = (const int*)d_in[7];
  float*       out   = (float*)d_out;

  const int V = in_sizes[0] / 3;
  const int F = in_sizes[6] / 3;
  const int P = in_sizes[4] / kK;  // N*H*W pixels

  float* vs = (float*)d_ws;
  size_t vsBytes = (size_t)V * 3 * sizeof(float);
  size_t fcOff   = (vsBytes + 255) & ~(size_t)255;
  size_t fcBytes = (size_t)F * 9 * sizeof(float);
  bool useFC = (fcOff + fcBytes) <= ws_size;
  float* fcbuf = (float*)((char*)d_ws + fcOff);

  shade_verts_kernel<<<(V + 255) / 256, 256, 0, stream>>>(vn, vc, sh, vs, V);
  if (useFC) {
    face_colors_kernel<<<(F + 255) / 256, 256, 0, stream>>>(faces, vs, fcbuf, F);
    blend_kernel<true><<<(P + 255) / 256, 256, 0, stream>>>(
        bary, zbuf, dists, p2f, fcbuf, faces, vs, out, P);
  } else {
    blend_kernel<false><<<(P + 255) / 256, 256, 0, stream>>>(
        bary, zbuf, dists, p2f, nullptr, faces, vs, out, P);
  }
}